// Round 14
// baseline (133.269 us; speedup 1.0000x reference)
//
#include <hip/hip_runtime.h>
#include <hip/hip_bf16.h>
#include <string.h>

// Problem constants
#define NB    4096      // batch rows
#define IND_  512       // feature dim
#define OUTD_ 512       // output dim (GEMM M, "o")
#define XCOLS 514       // P + IND
#define ND    25        // D^P
#define KTOT  12800     // IND_*ND

// Wt (fragment-order W) geometry: Wt[d][og][iw][lane][32]
//   d in [0,25), og in [0,32) (16-row o-groups), iw in [0,4), lane in [0,64)
//   d-stride = 32*4*2048 = 262144; bias block at WT_BIAS + og*2048
#define WT_DS   262144
#define WT_BIAS 6553600   // 25*262144; +32*2048 = 6,619,136 total

// GEMM tiling (v15: 16o x 128b block, 4 waves x (16o x 32b) sharing one og,
//              grid 1024 -> 4 blocks/CU -> 4 waves/SIMD naturally;
//              v14-proven unchained acc + deferred flush)
#define BM 16
#define BN 128

// prep_w tiling (R18-proven v2 load stage)
#define PWI 64
#define PWO 4
#define PWC (PWO * ND)   // 100 columns (o_l*25 + d)
#define T8P 112          // tile8 padded byte stride

typedef float  f32x4  __attribute__((ext_vector_type(4)));
typedef int    i32x4  __attribute__((ext_vector_type(4)));
typedef int    i32x8  __attribute__((ext_vector_type(8)));
typedef unsigned int   u32x2 __attribute__((ext_vector_type(2)));

// Software fp32 -> OCP e4m3fn, RNE, for v >= 0 (all values < 1.2).
__device__ __forceinline__ unsigned char f2fp8(float v) {
  if (v < 0.015625f) {
    return (unsigned char)__float2int_rn(v * 512.0f);
  }
  unsigned int u = __float_as_uint(v);
  u += 0x7ffffu + ((u >> 20) & 1u);
  int e = (int)(u >> 23) - 127 + 7;
  unsigned int m = (u >> 20) & 7u;
  return (unsigned char)((e << 3) | m);
}

__device__ __forceinline__ float basis_f(float t, int j) {
  switch (j) {
    case 0: return 1.0f;
    case 1: return t;
    case 2: return t * t;
    case 3: { float r = t - 0.33f; r = r > 0.0f ? r : 0.0f; return r * r; }
    default:{ float r = t - 0.66f; r = r > 0.0f ? r : 0.0f; return r * r; }
  }
}

// ---------------------------------------------------------------------------
// prep_all v5 (R13-proven, unchanged): fragment-order Wt, kv stored
// directly in kbKV [d][bt][l15][nf], kbT8, bias block in Wt.
// ---------------------------------------------------------------------------
__global__ __launch_bounds__(256) void prep_all_kernel(
    const float* __restrict__ x, const float* __restrict__ W,
    const float* __restrict__ bias, unsigned char* __restrict__ Xf8,
    float* __restrict__ kbKV, unsigned char* __restrict__ kbT8,
    unsigned char* __restrict__ Wt, float* __restrict__ out)
{
  __shared__ unsigned char tile8[PWI * T8P];   // 7 KB
  const int bid = blockIdx.x;
  const int tid = threadIdx.x;

  if (bid < 512) {
    const int lane = tid & 63;
    #pragma unroll
    for (int rr = 0; rr < 2; ++rr) {
      const int b = bid * 8 + (tid >> 6) * 2 + rr;
      const float* xr = x + (size_t)b * XCOLS;
      const float* fp = xr + 2 + lane * 8;
      float2 a0 = *(const float2*)(fp + 0);
      float2 a1 = *(const float2*)(fp + 2);
      float2 a2 = *(const float2*)(fp + 4);
      float2 a3 = *(const float2*)(fp + 6);
      float xf[8] = {a0.x, a0.y, a1.x, a1.y, a2.x, a2.y, a3.x, a3.y};
      u32x2 pk;
      pk[0] = (unsigned int)f2fp8(xf[0]) | ((unsigned int)f2fp8(xf[1]) << 8) |
              ((unsigned int)f2fp8(xf[2]) << 16) | ((unsigned int)f2fp8(xf[3]) << 24);
      pk[1] = (unsigned int)f2fp8(xf[4]) | ((unsigned int)f2fp8(xf[5]) << 8) |
              ((unsigned int)f2fp8(xf[6]) << 16) | ((unsigned int)f2fp8(xf[7]) << 24);
      *reinterpret_cast<u32x2*>(Xf8 + (size_t)b * IND_ + lane * 8) = pk;

      float t0 = xr[0], t1 = xr[1];
      if (lane < 2) out[(size_t)b * XCOLS + lane] = (lane == 0) ? t0 : t1;
      {
        // kv_d stored directly (unchained acc, direct weighting)
        int d1 = lane / 5, d2 = lane - d1 * 5;
        float kvd = basis_f(t0, d1) * basis_f(t1, d2);
        if (lane < ND) {
          int bt = b >> 7, bl = b & 15, nf = (b >> 4) & 7;
          kbKV[(((size_t)lane * 32 + bt) * 16 + bl) * 8 + nf] = kvd;
        }
      }
      {
        int ta = 2 * lane, tb = 2 * lane + 1;
        unsigned char ba = 0, bb = 0;
        if (ta < ND) { int d1 = ta / 5, d2 = ta - d1 * 5;
                       ba = f2fp8(basis_f(t0, d1) * basis_f(t1, d2)); }
        if (tb < ND) { int d1 = tb / 5, d2 = tb - d1 * 5;
                       bb = f2fp8(basis_f(t0, d1) * basis_f(t1, d2)); }
        *(unsigned short*)(kbT8 + (size_t)b * 128 + 2 * lane) =
            (unsigned short)ba | ((unsigned short)bb << 8);
      }
    }
  } else {
    const int pw = bid - 512;
    const int i0 = (pw & 7) * PWI;
    const int o0 = (pw >> 3) * PWO;

    for (int t = tid; t < PWI * (PWC / 4); t += 256) {
      int il = t / (PWC / 4);
      int c4 = t - il * (PWC / 4);
      float4 v = *(const float4*)(W + ((size_t)(i0 + il) * OUTD_ + o0) * ND + c4 * 4);
      unsigned int pk = (unsigned int)f2fp8(v.x) | ((unsigned int)f2fp8(v.y) << 8) |
                        ((unsigned int)f2fp8(v.z) << 16) | ((unsigned int)f2fp8(v.w) << 24);
      *(unsigned int*)&tile8[il * T8P + c4 * 4] = pk;
    }
    __syncthreads();

    // byte-gather into FRAGMENT-ORDER Wt:
    //   dest(d, o, ib) = (((d*32 + o>>4)*4 + ib>>7)*2048
    //                    + ((ib&127)>>5)*512 + (o&15)*32 + (ib&31)
    for (int g = tid; g < PWC * (PWI / 8); g += 256) {
      int c  = g >> 3;
      int ig = g & 7;
      int d  = c % 25;
      int o_l = c / 25;
      unsigned long long v = 0;
      #pragma unroll
      for (int jj = 0; jj < 8; ++jj)
        v |= (unsigned long long)tile8[(ig * 8 + jj) * T8P + c] << (8 * jj);
      int o  = o0 + o_l;
      int ib = i0 + ig * 8;            // [0,512)
      int iw = ib >> 7;
      int wb = ib & 127;
      size_t dest = (((size_t)d * 32 + (o >> 4)) * 4 + iw) * 2048
                  + (size_t)(((wb >> 5) * 16 + (o & 15)) * 32 + (wb & 31));
      *reinterpret_cast<unsigned long long*>(Wt + dest) = v;
    }

    if ((pw & 7) == 0) {
      // bias block: fragment order at WT_BIAS + og*2048
      int o = o0 + (tid >> 6);
      int p = tid & 63;
      int ta = 2 * p, tb = 2 * p + 1;
      unsigned char ba = (ta < ND) ? f2fp8(bias[o * ND + ta]) : (unsigned char)0;
      unsigned char bb = (tb < ND) ? f2fp8(bias[o * ND + tb]) : (unsigned char)0;
      size_t dest = WT_BIAS + (size_t)(o >> 4) * 2048
                  + (size_t)(((ta >> 5) * 16 + (o & 15)) * 32 + (ta & 31));
      *(unsigned short*)(Wt + dest) =
          (unsigned short)ba | ((unsigned short)bb << 8);
    }
  }
}

// ---------------------------------------------------------------------------
// gemm_out v15: LIGHT WAVES, 4 waves/SIMD by grid, v14 dataflow.
//
// R30 post-mortem of v14: unchained acc + deferred flush gained ~5 us
// (gemm ~43.5 -> ~38.5; dur 123.6 -> 118.4, new best).  But grid 512 =
// 2 blocks/CU = 2 waves/SIMD — GRID-limited TLP, registers would allow 3.
// Every previous TLP attempt spilled because it capped registers around
// a fat wave (R9/R25/R27 ledger).  v15 inverts: halve the WAVE so 4
// waves/SIMD fit with no allocator pressure.
//
// Wave tile 16o x 32b (2 MFMA/iter, bfr[2], fin[2]); block = 16o x 128b,
// 4 waves SHARE one og -> identical A addresses, L1 broadcast.  Grid
// 1024 = 32 og x 32 by = 4 blocks/CU = 16 waves/CU = 4 waves/SIMD.
// Regs ~80 arch + 24 accum ~= 104: below every cap ((256,3) kept — cap
// 170, pure slack; (256,4)'s 64/64 split would squeeze, avoided per R27).
// MFMA floor unchanged (4w x 2 MFMA x 34.5 = 276 cyc/SIMD-iter, 104
// iters = 12 us); latency hiding doubles, per-wave VMEM halves.
// v14-proven: unchained acc(n)=mfma(a,b,0), flush fin += q*acc one iter
// late (q now float2), 2-unroll parity passes, depth-2 A prefetch.
// Overruns (A<=26, q<=27) land in kbKV/kbT8 — in-ws, discarded.
// SPILL TRIPWIRE: WRITE > 12 MB.  FALSIFIER: dur unchanged +-2 us with
// clean WRITE => TLP conclusively not the lever; pivot to prep_all.
// ---------------------------------------------------------------------------
__global__ __launch_bounds__(256, 3) void gemm_out_kernel(
    const unsigned char* __restrict__ Wt, const unsigned char* __restrict__ Xf8,
    const float* __restrict__ kbKV, const unsigned char* __restrict__ kbT8,
    float* __restrict__ out)
{
  const int tid  = threadIdx.x;
  const int lane = tid & 63;
  const int w    = tid >> 6;            // [0,4): b-quarter
  const int l15  = lane & 15;
  const int quad = lane >> 4;

  const int id = blockIdx.x;            // [0,1024)
  const int og = ((id & 7) << 2) | ((id >> 3) & 3);   // [0,32), XCD-grouped
  const int by = id >> 5;               // [0,32)

  const int b0 = by * BN;
  const int bq = b0 + w * 32;           // wave's 32 b-cols

  // helper: load a 32-B fragment into i32x8
  auto load8 = [](const unsigned char* p) -> i32x8 {
    i32x4 lo = *reinterpret_cast<const i32x4*>(p);
    i32x4 hi = *reinterpret_cast<const i32x4*>(p + 16);
    i32x8 v;
    v[0] = lo[0]; v[1] = lo[1]; v[2] = lo[2]; v[3] = lo[3];
    v[4] = hi[0]; v[5] = hi[1]; v[6] = hi[2]; v[7] = hi[3];
    return v;
  };

  f32x4 fin[2];
  #pragma unroll
  for (int nf = 0; nf < 2; ++nf) fin[nf] = (f32x4)0.0f;

  const f32x4 Z = (f32x4)0.0f;
  // q (float2) address: kbKV float-offset d*4096 + by*128 + l15*8 + w*2
  const float* dBase = kbKV + (size_t)by * 128 + l15 * 8 + w * 2;

  // ---- iw loop: 4 x 25-iter d-loop, unchained acc, deferred flush ----
  for (int iw = 0; iw < 4; ++iw) {
    // B fragments for this i-window: 16 regs
    i32x8 bfr[2];
    #pragma unroll
    for (int nf = 0; nf < 2; ++nf)
      bfr[nf] = load8(Xf8 + (size_t)(bq + nf * 16 + l15) * IND_
                          + iw * 128 + quad * 32);

    const unsigned char* aP = Wt + ((size_t)og * 4 + iw) * 2048 + lane * 32;
    const float* dP = dBase;

    // 2 independent MFMAs, C = 0 (no cross-iter chain)
    f32x4 accA[2], accB[2];
    auto mfma2A = [&](const i32x8& a) {
      #pragma unroll
      for (int nf = 0; nf < 2; ++nf)
        accA[nf] = __builtin_amdgcn_mfma_scale_f32_16x16x128_f8f6f4(
            a, bfr[nf], Z, 0, 0, 0, 0x7f7f7f7f, 0, 0x7f7f7f7f);
    };
    auto mfma2B = [&](const i32x8& a) {
      #pragma unroll
      for (int nf = 0; nf < 2; ++nf)
        accB[nf] = __builtin_amdgcn_mfma_scale_f32_16x16x128_f8f6f4(
            a, bfr[nf], Z, 0, 0, 0, 0x7f7f7f7f, 0, 0x7f7f7f7f);
    };
    auto flushA = [&](const float2& q) {
      #pragma unroll
      for (int r = 0; r < 4; ++r) {
        fin[0][r] += q.x * accA[0][r];
        fin[1][r] += q.y * accA[1][r];
      }
    };
    auto flushB = [&](const float2& q) {
      #pragma unroll
      for (int r = 0; r < 4; ++r) {
        fin[0][r] += q.x * accB[0][r];
        fin[1][r] += q.y * accB[1][r];
      }
    };

    // prologue: A(0), A(1); q(0), q(1)
    i32x8 a0 = load8(aP);
    i32x8 a1 = load8(aP + WT_DS);
    float2 qA = *reinterpret_cast<const float2*>(dP);
    float2 qB = *reinterpret_cast<const float2*>(dP + 4096);

    // peel iter 0: acc(0) into accA; reload a0 <- A(2)
    mfma2A(a0);
    a0 = load8(aP + 2 * WT_DS);

    // 12 passes x 2 iters: n = 2p+1 (accB), 2p+2 (accA).
    // Flush of acc(n) happens AFTER iter n+1's MFMAs are issued.
    for (int p = 0; p < 12; ++p) {
      // iter 2p+1:
      mfma2B(a1);                                        // A(2p+1)
      a1 = load8(aP + 3 * WT_DS);                        // A(2p+3)
      float2 qC = *reinterpret_cast<const float2*>(dP + 2 * 4096); // q(2p+2)
      flushA(qA);                                        // acc(2p), covered
      // iter 2p+2:
      mfma2A(a0);                                        // A(2p+2)
      a0 = load8(aP + 4 * WT_DS);                        // A(2p+4); p=11 ->
      float2 qD = *reinterpret_cast<const float2*>(dP + 3 * 4096); //  in-ws
      flushB(qB);                                        // acc(2p+1)
      qA = qC; qB = qD;
      aP += 2 * WT_DS;
      dP += 2 * 4096;
    }
    // epilogue: acc(24) in accA, qA = q(24)
    flushA(qA);
  }

  // ---- bias K-tail (once): A = bias block, B = kbT8, kv = 1 -> into fin
  {
    i32x8 ab = load8(Wt + WT_BIAS + (size_t)og * 2048 + lane * 32);
    i32x8 bft[2];
    #pragma unroll
    for (int nf = 0; nf < 2; ++nf)
      bft[nf] = load8(kbT8 + (size_t)(bq + nf * 16 + l15) * 128 + quad * 32);
    #pragma unroll
    for (int nf = 0; nf < 2; ++nf)
      fin[nf] = __builtin_amdgcn_mfma_scale_f32_16x16x128_f8f6f4(
          ab, bft[nf], fin[nf], 0, 0, 0, 0x7f7f7f7f, 0, 0x7f7f7f7f);
  }

  // ---- fused relu + direct f32 store to out ----
  #pragma unroll
  for (int nf = 0; nf < 2; ++nf) {
    int bg = bq + nf * 16 + l15;
    int oo = og * 16 + quad * 4;
    float* op = out + (size_t)bg * XCOLS + 2 + oo;   // 8B-aligned
    float2 lo, hi;
    lo.x = fin[nf][0] > 0.0f ? fin[nf][0] : 0.0f;
    lo.y = fin[nf][1] > 0.0f ? fin[nf][1] : 0.0f;
    hi.x = fin[nf][2] > 0.0f ? fin[nf][2] : 0.0f;
    hi.y = fin[nf][3] > 0.0f ? fin[nf][3] : 0.0f;
    *(float2*)op = lo;
    *(float2*)(op + 2) = hi;
  }
}

// ---------------------------------------------------------------------------
extern "C" void kernel_launch(void* const* d_in, const int* in_sizes, int n_in,
                              void* d_out, int out_size, void* d_ws, size_t ws_size,
                              hipStream_t stream) {
  const float* x    = (const float*)d_in[0];   // 4096 x 514
  const float* W    = (const float*)d_in[1];   // 512 x 512 x 25
  const float* bias = (const float*)d_in[2];   // 512 x 25
  float* out = (float*)d_out;
  char* ws = (char*)d_ws;

  // ws layout (bytes):
  //   Xf8 2,097,152 | Wt 6,619,136 | kbKV 25*4096*4 = 409,600
  //   kbT8 524,288   (no split-K, no Pb)
  const size_t xf_off  = 0;
  const size_t wf_off  = 2097152;
  const size_t kb_off  = wf_off + 6619136;
  const size_t kbt_off = kb_off + 409600;
  unsigned char* Xf8  = (unsigned char*)(ws + xf_off);
  unsigned char* Wt   = (unsigned char*)(ws + wf_off);
  float* kbKV         = (float*)(ws + kb_off);
  unsigned char* kbT8 = (unsigned char*)(ws + kbt_off);

  prep_all_kernel<<<1536, 256, 0, stream>>>(x, W, bias, Xf8, kbKV, kbT8, Wt, out);
  gemm_out_kernel<<<1024, 256, 0, stream>>>(Wt, Xf8, kbKV, kbT8, out);
}

// Round 15
// 113.546 us; speedup vs baseline: 1.1737x; 1.1737x over previous
//
#include <hip/hip_runtime.h>
#include <hip/hip_bf16.h>
#include <string.h>

// Problem constants
#define NB    4096      // batch rows
#define IND_  512       // feature dim
#define OUTD_ 512       // output dim (GEMM M, "o")
#define XCOLS 514       // P + IND
#define ND    25        // D^P
#define KTOT  12800     // IND_*ND

// Wt (fragment-order W) geometry: Wt[d][og][iw][lane][32]
//   d-stride = 262144; bias block at WT_BIAS + og*2048
#define WT_DS   262144
#define WT_BIAS 6553600   // 25*262144; +32*2048 = 6,619,136 total

// GEMM tiling (v16: v14 structure — 32o x 128b block, 4 waves x (16o x 64b)
//              — with 3-buffer acc rotation: flush deferred TWO iters)
#define BM 32
#define BN 128

// prep_w tiling (R18-proven v2 load stage, R31: loads hoisted)
#define PWI 64
#define PWO 4
#define PWC (PWO * ND)   // 100 columns (o_l*25 + d)
#define T8P 112          // tile8 padded byte stride

typedef float  f32x4  __attribute__((ext_vector_type(4)));
typedef int    i32x4  __attribute__((ext_vector_type(4)));
typedef int    i32x8  __attribute__((ext_vector_type(8)));
typedef unsigned int   u32x2 __attribute__((ext_vector_type(2)));

// Software fp32 -> OCP e4m3fn, RNE, for v >= 0 (all values < 1.2).
__device__ __forceinline__ unsigned char f2fp8(float v) {
  if (v < 0.015625f) {
    return (unsigned char)__float2int_rn(v * 512.0f);
  }
  unsigned int u = __float_as_uint(v);
  u += 0x7ffffu + ((u >> 20) & 1u);
  int e = (int)(u >> 23) - 127 + 7;
  unsigned int m = (u >> 20) & 7u;
  return (unsigned char)((e << 3) | m);
}

__device__ __forceinline__ float basis_f(float t, int j) {
  switch (j) {
    case 0: return 1.0f;
    case 1: return t;
    case 2: return t * t;
    case 3: { float r = t - 0.33f; r = r > 0.0f ? r : 0.0f; return r * r; }
    default:{ float r = t - 0.66f; r = r > 0.0f ? r : 0.0f; return r * r; }
  }
}

// ---------------------------------------------------------------------------
// prep_all v6: SAME layouts as v5 (fragment-order Wt, kv in kbKV, kbT8,
// bias block) but ALL GLOBAL LOADS HOISTED ahead of their first use.
// R31 diagnosis: prep was ~25-30 us vs a ~7 us HBM floor because the load
// loops chained 7 (prep_w) / 8 (prep_x) cold-HBM loads per thread with the
// convert consuming each load immediately (zero overlap, ~900 cyc each).
// Hoisting puts all of a thread's loads in flight simultaneously.
// ---------------------------------------------------------------------------
__global__ __launch_bounds__(256) void prep_all_kernel(
    const float* __restrict__ x, const float* __restrict__ W,
    const float* __restrict__ bias, unsigned char* __restrict__ Xf8,
    float* __restrict__ kbKV, unsigned char* __restrict__ kbT8,
    unsigned char* __restrict__ Wt, float* __restrict__ out)
{
  __shared__ unsigned char tile8[PWI * T8P];   // 7 KB
  const int bid = blockIdx.x;
  const int tid = threadIdx.x;

  if (bid < 512) {
    const int lane = tid & 63;
    const int bb = bid * 8 + (tid >> 6) * 2;       // rows bb, bb+1
    const float* xr0 = x + (size_t)bb * XCOLS;
    const float* xr1 = xr0 + XCOLS;
    const float* fp0 = xr0 + 2 + lane * 8;
    const float* fp1 = xr1 + 2 + lane * 8;

    // hoisted loads: both rows' feature chunks + treatment scalars in flight
    float2 c0[4], c1[4];
    #pragma unroll
    for (int j = 0; j < 4; ++j) c0[j] = *(const float2*)(fp0 + 2 * j);
    #pragma unroll
    for (int j = 0; j < 4; ++j) c1[j] = *(const float2*)(fp1 + 2 * j);
    float t00 = xr0[0], t01 = xr0[1];
    float t10 = xr1[0], t11 = xr1[1];

    auto do_row = [&](int b, const float2* a, float t0, float t1) {
      float xf[8] = {a[0].x, a[0].y, a[1].x, a[1].y,
                     a[2].x, a[2].y, a[3].x, a[3].y};
      u32x2 pk;
      pk[0] = (unsigned int)f2fp8(xf[0]) | ((unsigned int)f2fp8(xf[1]) << 8) |
              ((unsigned int)f2fp8(xf[2]) << 16) | ((unsigned int)f2fp8(xf[3]) << 24);
      pk[1] = (unsigned int)f2fp8(xf[4]) | ((unsigned int)f2fp8(xf[5]) << 8) |
              ((unsigned int)f2fp8(xf[6]) << 16) | ((unsigned int)f2fp8(xf[7]) << 24);
      *reinterpret_cast<u32x2*>(Xf8 + (size_t)b * IND_ + lane * 8) = pk;

      if (lane < 2) out[(size_t)b * XCOLS + lane] = (lane == 0) ? t0 : t1;
      {
        // kv_d stored directly (unchained acc, direct weighting)
        int d1 = lane / 5, d2 = lane - d1 * 5;
        float kvd = basis_f(t0, d1) * basis_f(t1, d2);
        if (lane < ND) {
          int bt = b >> 7, bl = b & 15, nf = (b >> 4) & 7;
          kbKV[(((size_t)lane * 32 + bt) * 16 + bl) * 8 + nf] = kvd;
        }
      }
      {
        int ta = 2 * lane, tb = 2 * lane + 1;
        unsigned char ba = 0, bbb = 0;
        if (ta < ND) { int d1 = ta / 5, d2 = ta - d1 * 5;
                       ba = f2fp8(basis_f(t0, d1) * basis_f(t1, d2)); }
        if (tb < ND) { int d1 = tb / 5, d2 = tb - d1 * 5;
                       bbb = f2fp8(basis_f(t0, d1) * basis_f(t1, d2)); }
        *(unsigned short*)(kbT8 + (size_t)b * 128 + 2 * lane) =
            (unsigned short)ba | ((unsigned short)bbb << 8);
      }
    };
    do_row(bb, c0, t00, t01);
    do_row(bb + 1, c1, t10, t11);
  } else {
    const int pw = bid - 512;
    const int i0 = (pw & 7) * PWI;
    const int o0 = (pw >> 3) * PWO;

    // hoisted load stage: 1600 float4 over 256 threads = 6 full + 64 extra.
    // All of a thread's loads issue before any convert (latency overlap).
    float4 vv[7];
    #pragma unroll
    for (int k = 0; k < 6; ++k) {
      int t = tid + k * 256;
      int il = t / 25, c4 = t - il * 25;
      vv[k] = *(const float4*)(W + ((size_t)(i0 + il) * OUTD_ + o0) * ND + c4 * 4);
    }
    if (tid < 64) {
      int t = tid + 1536;
      int il = t / 25, c4 = t - il * 25;
      vv[6] = *(const float4*)(W + ((size_t)(i0 + il) * OUTD_ + o0) * ND + c4 * 4);
    }
    #pragma unroll
    for (int k = 0; k < 6; ++k) {
      int t = tid + k * 256;
      int il = t / 25, c4 = t - il * 25;
      unsigned int pk = (unsigned int)f2fp8(vv[k].x) | ((unsigned int)f2fp8(vv[k].y) << 8) |
                        ((unsigned int)f2fp8(vv[k].z) << 16) | ((unsigned int)f2fp8(vv[k].w) << 24);
      *(unsigned int*)&tile8[il * T8P + c4 * 4] = pk;
    }
    if (tid < 64) {
      int t = tid + 1536;
      int il = t / 25, c4 = t - il * 25;
      unsigned int pk = (unsigned int)f2fp8(vv[6].x) | ((unsigned int)f2fp8(vv[6].y) << 8) |
                        ((unsigned int)f2fp8(vv[6].z) << 16) | ((unsigned int)f2fp8(vv[6].w) << 24);
      *(unsigned int*)&tile8[il * T8P + c4 * 4] = pk;
    }
    __syncthreads();

    // byte-gather into FRAGMENT-ORDER Wt (unchanged):
    for (int g = tid; g < PWC * (PWI / 8); g += 256) {
      int c  = g >> 3;
      int ig = g & 7;
      int d  = c % 25;
      int o_l = c / 25;
      unsigned long long v = 0;
      #pragma unroll
      for (int jj = 0; jj < 8; ++jj)
        v |= (unsigned long long)tile8[(ig * 8 + jj) * T8P + c] << (8 * jj);
      int o  = o0 + o_l;
      int ib = i0 + ig * 8;            // [0,512)
      int iw = ib >> 7;
      int wb = ib & 127;
      size_t dest = (((size_t)d * 32 + (o >> 4)) * 4 + iw) * 2048
                  + (size_t)(((wb >> 5) * 16 + (o & 15)) * 32 + (wb & 31));
      *reinterpret_cast<unsigned long long*>(Wt + dest) = v;
    }

    if ((pw & 7) == 0) {
      // bias block: fragment order at WT_BIAS + og*2048
      int o = o0 + (tid >> 6);
      int p = tid & 63;
      int ta = 2 * p, tb = 2 * p + 1;
      unsigned char ba = (ta < ND) ? f2fp8(bias[o * ND + ta]) : (unsigned char)0;
      unsigned char bbb = (tb < ND) ? f2fp8(bias[o * ND + tb]) : (unsigned char)0;
      size_t dest = WT_BIAS + (size_t)(o >> 4) * 2048
                  + (size_t)(((ta >> 5) * 16 + (o & 15)) * 32 + (ta & 31));
      *(unsigned short*)(Wt + dest) =
          (unsigned short)ba | ((unsigned short)bbb << 8);
    }
  }
}

// ---------------------------------------------------------------------------
// gemm_out v16: v14 structure (PROVEN 118.4 us) + 3-buffer acc rotation.
//
// R31 post-mortem of v15: light-wave 4-waves/SIMD regressed (56.4 us,
// clean WRITE, occ 36.5%) — TLP is conclusively NOT the lever (falsifier
// fired).  Reverting to v14's 32o x 128b / 4-wave / grid-512 shape.
// The one v14 lever that paid (+5 us) was acc-unchaining + 1-iter flush
// deferral; v16 extends deferral to TWO iters (acc A/B/C rotation, flush
// acc(n) after iter n+1's AND part of n+2's MFMAs are issued ≈ 550 cyc
// of MFMA-completion cover), A prefetched 3 ahead, q 3 ahead.
// __launch_bounds__(256,2): cap 256, zero squeeze risk (R4/R7/R9 ledger);
// occupancy is grid-limited at 2 blocks/CU regardless.
// Regs ~98 arch + 64 accum ~= 162.  Overruns: A(25) and q(24) — A(25)
// lands in kbKV (in-ws, discarded); q(24) in-bounds.
// ---------------------------------------------------------------------------
__global__ __launch_bounds__(256, 2) void gemm_out_kernel(
    const unsigned char* __restrict__ Wt, const unsigned char* __restrict__ Xf8,
    const float* __restrict__ kbKV, const unsigned char* __restrict__ kbT8,
    float* __restrict__ out)
{
  const int tid  = threadIdx.x;
  const int lane = tid & 63;
  const int w    = tid >> 6;            // [0,4)
  const int l15  = lane & 15;
  const int quad = lane >> 4;

  const int id = blockIdx.x;            // [0,512)
  const int ox = ((id & 7) << 1) | ((id >> 3) & 1);   // [0,16), XCD-paired
  const int by = id >> 4;               // [0,32)

  const int o0 = ox * BM;               // 32-row o-tile base
  const int b0 = by * BN;

  const int og = ox * 2 + (w >> 1);     // global 16-row o-group [0,32)
  const int bh = w & 1;                 // b-half (64 cols)

  auto load8 = [](const unsigned char* p) -> i32x8 {
    i32x4 lo = *reinterpret_cast<const i32x4*>(p);
    i32x4 hi = *reinterpret_cast<const i32x4*>(p + 16);
    i32x8 v;
    v[0] = lo[0]; v[1] = lo[1]; v[2] = lo[2]; v[3] = lo[3];
    v[4] = hi[0]; v[5] = hi[1]; v[6] = hi[2]; v[7] = hi[3];
    return v;
  };

  f32x4 fin[4];
  #pragma unroll
  for (int nf = 0; nf < 4; ++nf) fin[nf] = (f32x4)0.0f;

  const f32x4 Z = (f32x4)0.0f;
  const float* dBase = kbKV + (((size_t)by * 16 + l15) * 8) + bh * 4;

  // ---- iw loop: 4 x 25-iter d-loop, unchained acc, 2-iter-deferred flush
  for (int iw = 0; iw < 4; ++iw) {
    i32x8 bfr[4];
    #pragma unroll
    for (int nf = 0; nf < 4; ++nf)
      bfr[nf] = load8(Xf8 + (size_t)(b0 + bh * 64 + nf * 16 + l15) * IND_
                          + iw * 128 + quad * 32);

    const unsigned char* aP = Wt + ((size_t)og * 4 + iw) * 2048 + lane * 32;
    const float* dP = dBase;            // q(n) at dP + n*4096

    f32x4 accA[4], accB[4], accC[4];
    auto mfmaA = [&](const i32x8& a) {
      #pragma unroll
      for (int nf = 0; nf < 4; ++nf)
        accA[nf] = __builtin_amdgcn_mfma_scale_f32_16x16x128_f8f6f4(
            a, bfr[nf], Z, 0, 0, 0, 0x7f7f7f7f, 0, 0x7f7f7f7f);
    };
    auto mfmaB = [&](const i32x8& a) {
      #pragma unroll
      for (int nf = 0; nf < 4; ++nf)
        accB[nf] = __builtin_amdgcn_mfma_scale_f32_16x16x128_f8f6f4(
            a, bfr[nf], Z, 0, 0, 0, 0x7f7f7f7f, 0, 0x7f7f7f7f);
    };
    auto mfmaC = [&](const i32x8& a) {
      #pragma unroll
      for (int nf = 0; nf < 4; ++nf)
        accC[nf] = __builtin_amdgcn_mfma_scale_f32_16x16x128_f8f6f4(
            a, bfr[nf], Z, 0, 0, 0, 0x7f7f7f7f, 0, 0x7f7f7f7f);
    };
    auto flushA = [&](const f32x4& q) {
      #pragma unroll
      for (int nf = 0; nf < 4; ++nf)
        #pragma unroll
        for (int r = 0; r < 4; ++r) fin[nf][r] += q[nf] * accA[nf][r];
    };
    auto flushB = [&](const f32x4& q) {
      #pragma unroll
      for (int nf = 0; nf < 4; ++nf)
        #pragma unroll
        for (int r = 0; r < 4; ++r) fin[nf][r] += q[nf] * accB[nf][r];
    };
    auto flushC = [&](const f32x4& q) {
      #pragma unroll
      for (int nf = 0; nf < 4; ++nf)
        #pragma unroll
        for (int r = 0; r < 4; ++r) fin[nf][r] += q[nf] * accC[nf][r];
    };

    // prologue: A(0..2), q(0..2)
    i32x8 a0 = load8(aP);
    i32x8 a1 = load8(aP + WT_DS);
    i32x8 a2 = load8(aP + 2 * WT_DS);
    f32x4 q0 = *reinterpret_cast<const f32x4*>(dP);
    f32x4 q1 = *reinterpret_cast<const f32x4*>(dP + 4096);
    f32x4 q2 = *reinterpret_cast<const f32x4*>(dP + 2 * 4096);

    mfmaA(a0); a0 = load8(aP + 3 * WT_DS);   // iter 0; a0 <- A(3)
    mfmaB(a1); a1 = load8(aP + 4 * WT_DS);   // iter 1; a1 <- A(4)

    // 7 passes x 3 iters: n = 3p+2 (C), 3p+3 (A), 3p+4 (B).
    // flush(acc(n)) happens two iters after issue.
    for (int p = 0; p < 7; ++p) {
      mfmaC(a2); a2 = load8(aP + 5 * WT_DS);                   // A(3p+5)
      flushA(q0); q0 = *reinterpret_cast<const f32x4*>(dP + 3 * 4096);  // q(3p+3)
      mfmaA(a0); a0 = load8(aP + 6 * WT_DS);                   // A(3p+6)
      flushB(q1); q1 = *reinterpret_cast<const f32x4*>(dP + 4 * 4096);  // q(3p+4)
      mfmaB(a1); a1 = load8(aP + 7 * WT_DS);                   // A(3p+7); p=6 -> A(25) in-ws junk
      flushC(q2); q2 = *reinterpret_cast<const f32x4*>(dP + 5 * 4096);  // q(3p+5)
      aP += 3 * WT_DS;
      dP += 3 * 4096;
    }
    // post-loop: issued 0..22; a2 = A(23), a0 = A(24); q0=q(21), q1=q(22), q2=q(23)
    mfmaC(a2); flushA(q0);               // iter 23; flush acc(21)
    mfmaA(a0); flushB(q1);               // iter 24; flush acc(22)
    flushC(q2);                          // acc(23)
    f32x4 q24 = *reinterpret_cast<const f32x4*>(dP + 3 * 4096);  // q(24)
    flushA(q24);                         // acc(24)
  }

  // ---- bias K-tail (once): A = bias block, B = kbT8, kv = 1 -> into fin
  {
    i32x8 ab = load8(Wt + WT_BIAS + (size_t)og * 2048 + lane * 32);
    i32x8 bft[4];
    #pragma unroll
    for (int nf = 0; nf < 4; ++nf)
      bft[nf] = load8(kbT8 + (size_t)(b0 + bh * 64 + nf * 16 + l15) * 128
                           + quad * 32);
    #pragma unroll
    for (int nf = 0; nf < 4; ++nf)
      fin[nf] = __builtin_amdgcn_mfma_scale_f32_16x16x128_f8f6f4(
          ab, bft[nf], fin[nf], 0, 0, 0, 0x7f7f7f7f, 0, 0x7f7f7f7f);
  }

  // ---- fused relu + direct f32 store to out ----
  #pragma unroll
  for (int nf = 0; nf < 4; ++nf) {
    int bg = b0 + bh * 64 + nf * 16 + l15;
    int oo = o0 + (w >> 1) * 16 + quad * 4;
    float* op = out + (size_t)bg * XCOLS + 2 + oo;   // 8B-aligned
    float2 lo, hi;
    lo.x = fin[nf][0] > 0.0f ? fin[nf][0] : 0.0f;
    lo.y = fin[nf][1] > 0.0f ? fin[nf][1] : 0.0f;
    hi.x = fin[nf][2] > 0.0f ? fin[nf][2] : 0.0f;
    hi.y = fin[nf][3] > 0.0f ? fin[nf][3] : 0.0f;
    *(float2*)op = lo;
    *(float2*)(op + 2) = hi;
  }
}

// ---------------------------------------------------------------------------
extern "C" void kernel_launch(void* const* d_in, const int* in_sizes, int n_in,
                              void* d_out, int out_size, void* d_ws, size_t ws_size,
                              hipStream_t stream) {
  const float* x    = (const float*)d_in[0];   // 4096 x 514
  const float* W    = (const float*)d_in[1];   // 512 x 512 x 25
  const float* bias = (const float*)d_in[2];   // 512 x 25
  float* out = (float*)d_out;
  char* ws = (char*)d_ws;

  // ws layout (bytes):
  //   Xf8 2,097,152 | Wt 6,619,136 | kbKV 25*4096*4 = 409,600
  //   kbT8 524,288   (no split-K, no Pb)
  const size_t xf_off  = 0;
  const size_t wf_off  = 2097152;
  const size_t kb_off  = wf_off + 6619136;
  const size_t kbt_off = kb_off + 409600;
  unsigned char* Xf8  = (unsigned char*)(ws + xf_off);
  unsigned char* Wt   = (unsigned char*)(ws + wf_off);
  float* kbKV         = (float*)(ws + kb_off);
  unsigned char* kbT8 = (unsigned char*)(ws + kbt_off);

  prep_all_kernel<<<1536, 256, 0, stream>>>(x, W, bias, Xf8, kbKV, kbT8, Wt, out);
  gemm_out_kernel<<<512, 256, 0, stream>>>(Wt, Xf8, kbKV, kbT8, out);
}